// Round 13
// baseline (288.202 us; speedup 1.0000x reference)
//
#include <hip/hip_runtime.h>
#include <math.h>

#define Bb 8
#define Ll 1024
#define Dd 256
#define Ee 8
#define Hh 1024
#define LMAXc 512
#define NTOK (Bb*Dd)   // 2048
#define LPAD 1032      // 4 + 1024 + 4 padded token rows per batch
#define MAXTILES 72    // worst-case sum_e ceil(cnt[e]/64): 4096/64 + 7
#define MAXT128 39     // worst-case sum_e ceil(cnt[e]/128): 32 + 7

typedef short bf16x8 __attribute__((ext_vector_type(8)));
typedef float f32x4 __attribute__((ext_vector_type(4)));
typedef unsigned short u16x8 __attribute__((ext_vector_type(8)));

__device__ __forceinline__ float gelu_f(float x) {
    return 0.5f * x * (1.0f + erff(x * 0.70710678118654752440f));
}
__device__ __forceinline__ unsigned short f2b(float x) {          // RTN fp32->bf16
    unsigned int u = __float_as_uint(x);
    return (unsigned short)((u + 0x7fffu + ((u >> 16) & 1u)) >> 16);
}
__device__ __forceinline__ float b2f(unsigned short h) {
    return __uint_as_float(((unsigned int)h) << 16);
}
__device__ __forceinline__ void gl_lds16(const void* g, void* l) {
    __builtin_amdgcn_global_load_lds((const __attribute__((address_space(1))) unsigned int*)g,
                                     (__attribute__((address_space(3))) unsigned int*)l, 16, 0, 0);
}

// ============================================================================
// prep_all v4 (unchanged from R12)
// ============================================================================
__global__ __launch_bounds__(256) void prep_all(
    const float* __restrict__ x, const float* __restrict__ cw,
    unsigned short* __restrict__ xhi, unsigned short* __restrict__ xlo,
    unsigned short* __restrict__ chi, unsigned short* __restrict__ clo,
    unsigned short* __restrict__ wchi, unsigned short* __restrict__ wclo,
    float* __restrict__ zbase)
{
    int blk = blockIdx.x;
    int t = threadIdx.x;
    if (blk < 32) {
        // zero pad rows: 4 buffers x (8 batches x 8 rows x 256 elems)
        int u = blk * 256 + t;                     // [0, 8192)
        int f = u >> 11;
        int rem = u & 2047;
        int b = rem >> 8;
        int r2 = rem & 255;
        int row = r2 >> 5;
        int col = (r2 & 31) * 8;
        int padrow = (row < 4) ? row : (1024 + row);
        unsigned short* buf = (f == 0) ? xhi : (f == 1) ? xlo : (f == 2) ? chi : clo;
        u16x8 z = {0, 0, 0, 0, 0, 0, 0, 0};
        *(u16x8*)(buf + (size_t)(b * LPAD + padrow) * Dd + col) = z;
    } else if (blk < 288) {
        // x split: 262144 octs (8 floats), ILP4, 16B hi + 16B lo stores
        int cb = blk - 32;
        const float4* s4 = (const float4*)x;
        size_t ob = (size_t)cb * 1024 + t;
        float4 v[8];
        #pragma unroll
        for (int it = 0; it < 4; ++it) {
            v[2 * it]     = s4[(ob + it * 256) * 2];
            v[2 * it + 1] = s4[(ob + it * 256) * 2 + 1];
        }
        #pragma unroll
        for (int it = 0; it < 4; ++it) {
            size_t o = ob + it * 256;
            int d8 = (int)(o & 31), l = (int)((o >> 5) & 1023), b = (int)(o >> 15);
            size_t ooff = (size_t)(b * LPAD + 4 + l) * Dd + d8 * 8;
            float vv[8] = {v[2*it].x, v[2*it].y, v[2*it].z, v[2*it].w,
                           v[2*it+1].x, v[2*it+1].y, v[2*it+1].z, v[2*it+1].w};
            u16x8 hv, lv;
            #pragma unroll
            for (int q = 0; q < 8; ++q) {
                unsigned short h = f2b(vv[q]);
                hv[q] = (short)h;
                lv[q] = (short)f2b(vv[q] - b2f(h));
            }
            *(u16x8*)(xhi + ooff) = hv;
            *(u16x8*)(xlo + ooff) = lv;
        }
    } else if (blk < 576) {
        // conv weights: 589824 outputs; thread = 8 consecutive outputs
        int cb = blk - 288;                        // [0, 288)
        int idx0 = (cb * 256 + t) * 8;
        float vv[8];
        #pragma unroll
        for (int q = 0; q < 8; ++q) {
            int idx = idx0 + q;
            int i = idx & (Dd - 1);
            int o = (idx >> 8) & (Dd - 1);
            int lk = idx >> 16;
            int layer = lk / 3;
            int k = lk % 3;
            vv[q] = cw[(((size_t)layer * Dd + o) * Dd + i) * 3 + k];
        }
        u16x8 hv, lv;
        #pragma unroll
        for (int q = 0; q < 8; ++q) {
            unsigned short h = f2b(vv[q]);
            hv[q] = (short)h;
            lv[q] = (short)f2b(vv[q] - b2f(h));
        }
        *(u16x8*)(wchi + idx0) = hv;
        *(u16x8*)(wclo + idx0) = lv;
    } else {
        // zero logits (65536 B) + cnt (64 B) = 4100 x 16B
        int idx = (blk - 576) * 256 + t;
        if (idx < 4100) {
            u16x8 z = {0, 0, 0, 0, 0, 0, 0, 0};
            *(u16x8*)((char*)zbase + (size_t)idx * 16) = z;
        }
    }
}

// ============================================================================
// conv_mfma (R12 structure, 4 blocks/CU): dilated conv as MFMA NT-GEMM,
// 3-pass split, 64x64 tile, 4 waves (2x2 of 32x32), BK=64.
// MODE 0: split hi/lo output planes.  MODE 1: fused router-logits epilogue.
// CVT rows [4, 4+NCVT): stream fp32 expert weights -> bf16 planes.
// DS=1 (conv1 only): downsample x -> xe rides the CU slack.
// ============================================================================
template<int MODE, int CVT, int NCVT, int DS>
__global__ __launch_bounds__(256, 4) void conv_mfma(
    const unsigned short* __restrict__ inhi, const unsigned short* __restrict__ inlo,
    const unsigned short* __restrict__ whiL, const unsigned short* __restrict__ wloL,
    const float* __restrict__ bias,
    unsigned short* __restrict__ outhi, unsigned short* __restrict__ outlo,
    const float* __restrict__ flw, float* __restrict__ logits,
    const float* __restrict__ cvsrc, unsigned short* __restrict__ cvd1,
    unsigned short* __restrict__ cvd2,
    const float* __restrict__ dsx, unsigned short* __restrict__ dsxe, int dil)
{
    __shared__ char smem[32768];

    if (DS && blockIdx.y >= (Dd / 64) + NCVT) {
        // downsample: u = (e*8 + b)*64 + c;  j0 = c*8; threads = d
        int u = (blockIdx.y - (Dd / 64) - NCVT) * 128 + blockIdx.x;  // [0,4096)
        int e = u >> 9;
        int b = (u >> 6) & 7;
        int c = u & 63;
        int f = e + 2;
        int Li = Ll / f;
        int j0 = c * 8;
        if (j0 >= Li) return;
        int d = threadIdx.x;
        float invf = 1.0f / (float)f;
        int lim = Li - 1;
        float v[8] = {};
        for (int r = 0; r < f; ++r) {
            #pragma unroll
            for (int jj = 0; jj < 8; ++jj) {
                int j = j0 + jj; if (j > lim) j = lim;
                v[jj] += dsx[((size_t)(b * Ll + j * f + r)) * Dd + d];
            }
        }
        size_t obase = ((size_t)(e * NTOK + b * 256 + d)) * LMAXc + j0;
        if (j0 + 8 <= Li) {
            u16x8 hv;
            #pragma unroll
            for (int q = 0; q < 8; ++q) hv[q] = (short)f2b(v[q] * invf);
            *(u16x8*)(dsxe + obase) = hv;
        } else {
            for (int jj = 0; jj < Li - j0; ++jj)
                dsxe[obase + jj] = f2b(v[jj] * invf);
        }
        return;
    }

    if (CVT && blockIdx.y >= (Dd / 64)) {
        int cb = (blockIdx.y - Dd / 64) * 128 + blockIdx.x;
        int t = threadIdx.x;
        const float4* s4 = (const float4*)cvsrc;
        size_t ob = (size_t)cb * 1024 + t;
        float4 v[8];
        #pragma unroll
        for (int it = 0; it < 4; ++it) {
            v[2 * it]     = s4[(ob + it * 256) * 2];
            v[2 * it + 1] = s4[(ob + it * 256) * 2 + 1];
        }
        #pragma unroll
        for (int it = 0; it < 4; ++it) {
            size_t o = ob + it * 256;
            float vv[8] = {v[2*it].x, v[2*it].y, v[2*it].z, v[2*it].w,
                           v[2*it+1].x, v[2*it+1].y, v[2*it+1].z, v[2*it+1].w};
            u16x8 hv, lv;
            #pragma unroll
            for (int q = 0; q < 8; ++q) {
                unsigned short h = f2b(vv[q]);
                hv[q] = (short)h;
                if (CVT == 1) lv[q] = (short)f2b(vv[q] - b2f(h));
            }
            *(u16x8*)(cvd1 + o * 8) = hv;
            if (CVT == 1) *(u16x8*)(cvd2 + o * 8) = lv;
        }
        return;
    }

    char* sAhi = smem;
    char* sAlo = smem + 8192;
    char* sBhi = smem + 16384;
    char* sBlo = smem + 24576;

    const int t = threadIdx.x;
    const int lane = t & 63, w = t >> 6;
    const int r16 = lane & 15, quad = lane >> 4;
    const int wr = w >> 1, wc = w & 1;
    const int row0 = blockIdx.x * 64;
    const int col0 = blockIdx.y * 64;
    const int b = row0 >> 10, l0 = row0 & 1023;

    int aoff[2], boff[2];
    #pragma unroll
    for (int i = 0; i < 2; ++i) {
        int ra = wr * 32 + i * 16 + r16;
        aoff[i] = ra * 64 + ((quad ^ ((ra >> 1) & 3)) << 4);
        int rb = wc * 32 + i * 16 + r16;
        boff[i] = rb * 64 + ((quad ^ ((rb >> 1) & 3)) << 4);
    }
    const int rs = t >> 2, ce = ((t & 3) ^ ((rs >> 1) & 3)) << 3;
    const unsigned short* gAhi = inhi + (size_t)(b * LPAD + 4 + l0 + rs) * Dd + ce;
    const unsigned short* gAlo = inlo + (size_t)(b * LPAD + 4 + l0 + rs) * Dd + ce;

    f32x4 acc[2][2];
    const f32x4 zero4 = {0.f, 0.f, 0.f, 0.f};
    #pragma unroll
    for (int i = 0; i < 2; ++i)
        #pragma unroll
        for (int j = 0; j < 2; ++j) acc[i][j] = zero4;

    for (int tap = 0; tap < 3; ++tap) {
        const int sh = (tap - 1) * dil;
        const unsigned short* pAhi = gAhi + sh * Dd;
        const unsigned short* pAlo = gAlo + sh * Dd;
        const unsigned short* gBhi = whiL + ((size_t)tap * Dd + col0 + rs) * Dd + ce;
        const unsigned short* gBlo = wloL + ((size_t)tap * Dd + col0 + rs) * Dd + ce;
        for (int kb = 0; kb < Dd; kb += 64) {
            gl_lds16(pAhi + kb,      sAhi + (w << 10));
            gl_lds16(pAhi + kb + 32, sAhi + 4096 + (w << 10));
            gl_lds16(pAlo + kb,      sAlo + (w << 10));
            gl_lds16(pAlo + kb + 32, sAlo + 4096 + (w << 10));
            gl_lds16(gBhi + kb,      sBhi + (w << 10));
            gl_lds16(gBhi + kb + 32, sBhi + 4096 + (w << 10));
            gl_lds16(gBlo + kb,      sBlo + (w << 10));
            gl_lds16(gBlo + kb + 32, sBlo + 4096 + (w << 10));
            __syncthreads();
            #pragma unroll
            for (int h = 0; h < 2; ++h) {
                const int ho = h * 4096;
                bf16x8 ah[2], al[2], bh[2], bl[2];
                #pragma unroll
                for (int i = 0; i < 2; ++i) {
                    ah[i] = *(const bf16x8*)(sAhi + ho + aoff[i]);
                    al[i] = *(const bf16x8*)(sAlo + ho + aoff[i]);
                    bh[i] = *(const bf16x8*)(sBhi + ho + boff[i]);
                    bl[i] = *(const bf16x8*)(sBlo + ho + boff[i]);
                }
                #pragma unroll
                for (int mi = 0; mi < 2; ++mi)
                    #pragma unroll
                    for (int ni = 0; ni < 2; ++ni) {
                        acc[mi][ni] = __builtin_amdgcn_mfma_f32_16x16x32_bf16(ah[mi], bh[ni], acc[mi][ni], 0, 0, 0);
                        acc[mi][ni] = __builtin_amdgcn_mfma_f32_16x16x32_bf16(ah[mi], bl[ni], acc[mi][ni], 0, 0, 0);
                        acc[mi][ni] = __builtin_amdgcn_mfma_f32_16x16x32_bf16(al[mi], bh[ni], acc[mi][ni], 0, 0, 0);
                    }
            }
            __syncthreads();
        }
    }

    int cc[2]; float bv[2];
    #pragma unroll
    for (int ni = 0; ni < 2; ++ni) {
        cc[ni] = col0 + wc * 32 + ni * 16 + r16;
        bv[ni] = bias[cc[ni]];
    }
    if (MODE == 0) {
        #pragma unroll
        for (int mi = 0; mi < 2; ++mi) {
            int lb = l0 + wr * 32 + mi * 16 + quad * 4;
            #pragma unroll
            for (int reg = 0; reg < 4; ++reg) {
                int l = lb + reg;
                #pragma unroll
                for (int ni = 0; ni < 2; ++ni) {
                    float v = gelu_f(acc[mi][ni][reg] + bv[ni]);
                    size_t o = (size_t)(b * LPAD + 4 + l) * Dd + cc[ni];
                    unsigned short h = f2b(v);
                    outhi[o] = h;
                    outlo[o] = f2b(v - b2f(h));
                }
            }
        }
    } else {
        // fused logits: LDS partials over the 64x64 tile, then 512 atomics.
        float* wl   = (float*)smem;            // [64 l_local][8 e]
        float* slog = (float*)(smem + 2048);   // [64 d_local][8 e]
        for (int i = t; i < 512; i += 256) {
            int ll = i >> 3, e = i & 7;
            wl[i] = flw[e * Ll + l0 + ll];
            slog[i] = 0.0f;
        }
        __syncthreads();
        float part[2][8];
        #pragma unroll
        for (int ni = 0; ni < 2; ++ni)
            #pragma unroll
            for (int e = 0; e < 8; ++e) part[ni][e] = 0.0f;
        #pragma unroll
        for (int mi = 0; mi < 2; ++mi) {
            #pragma unroll
            for (int reg = 0; reg < 4; ++reg) {
                int ll = wr * 32 + mi * 16 + quad * 4 + reg;
                #pragma unroll
                for (int ni = 0; ni < 2; ++ni) {
                    float v = gelu_f(acc[mi][ni][reg] + bv[ni]);
                    #pragma unroll
                    for (int e = 0; e < 8; ++e) part[ni][e] += v * wl[ll * 8 + e];
                }
            }
        }
        #pragma unroll
        for (int ni = 0; ni < 2; ++ni) {
            int dl = wc * 32 + ni * 16 + r16;
            #pragma unroll
            for (int e = 0; e < 8; ++e) atomicAdd(&slog[dl * 8 + e], part[ni][e]);
        }
        __syncthreads();
        for (int i = t; i < 512; i += 256) {
            int dl = i >> 3, e = i & 7;
            atomicAdd(&logits[(size_t)(b * Dd + col0 + dl) * Ee + e], slog[i]);
        }
    }
}

// ============================================================================
// gemm_sp (64x64 tiles) — GEMM1 only (gather + two-pass split B + K-cap).
// ============================================================================
template<int MODE, int GATHER, int TWOPASS>
__global__ __launch_bounds__(256, 4) void gemm_sp(
    const unsigned short* __restrict__ AG,
    const unsigned short* __restrict__ BhiG, const unsigned short* __restrict__ BloG,
    const float* __restrict__ biasG, const float* __restrict__ gates,
    const int* __restrict__ cntG, const int* __restrict__ listG,
    unsigned short* __restrict__ Cout, float* __restrict__ outf,
    int M, int N, int K)
{
    // derive (expert, row-tile) from cnt prefix — uniform across the block
    int m = blockIdx.y, e;
    #pragma unroll
    for (e = 0; e < Ee; ++e) {
        int te = (cntG[e] + 63) >> 6;
        if (m < te) break;
        m -= te;
    }
    if (e == Ee) return;
    const int row0 = m * 64;
    const int cn = cntG[e];

    constexpr int NCH = TWOPASS ? 2 : 4;          // 32-col chunks per K-iter
    __shared__ char smem[TWOPASS ? 24576 : 32768];
    char* sA   = smem;
    char* sBhi = smem + NCH * 4096;
    char* sBlo = smem + 2 * NCH * 4096;           // TWOPASS only

    const unsigned short* Bhi = BhiG + (size_t)e * N * K;
    const unsigned short* Blo = TWOPASS ? (BloG + (size_t)e * N * K) : nullptr;
    const float* bias = biasG + (size_t)e * N;

    int Keff = K;
    if (GATHER) {
        int Li = Ll / (e + 2);
        Keff = ((Li + 63) >> 6) << 6;
    }

    const int t = threadIdx.x;
    const int lane = t & 63, w = t >> 6;
    const int r16 = lane & 15, quad = lane >> 4;
    const int wr = w >> 1, wc = w & 1;
    const int col0 = blockIdx.x * 64;

    int aoff[2], boff[2];
    #pragma unroll
    for (int i = 0; i < 2; ++i) {
        int ra = wr * 32 + i * 16 + r16;
        aoff[i] = ra * 64 + ((quad ^ ((ra >> 1) & 3)) << 4);
        int rb = wc * 32 + i * 16 + r16;
        boff[i] = rb * 64 + ((quad ^ ((rb >> 1) & 3)) << 4);
    }
    const int r0s = t >> 2, c0s = ((t & 3) ^ ((r0s >> 1) & 3)) << 3;
    int ri = row0 + r0s; if (ri > cn - 1) ri = cn - 1;
    const int ar = GATHER ? listG[e * NTOK + ri] : ri;
    const unsigned short* gA  = AG + ((size_t)e * M + ar) * K + c0s;
    const unsigned short* gB  = Bhi + (size_t)(col0 + r0s) * K + c0s;
    const unsigned short* gBl = TWOPASS ? (Blo + (size_t)(col0 + r0s) * K + c0s) : nullptr;
    const int wofs = w << 10;

    f32x4 acc[2][2];
    const f32x4 zero4 = {0.f, 0.f, 0.f, 0.f};
    #pragma unroll
    for (int i = 0; i < 2; ++i)
        #pragma unroll
        for (int j = 0; j < 2; ++j) acc[i][j] = zero4;

    for (int k0 = 0; k0 < Keff; k0 += NCH * 32) {
        #pragma unroll
        for (int c = 0; c < NCH; ++c) {
            gl_lds16(gA + k0 + c * 32, sA + c * 4096 + wofs);
            gl_lds16(gB + k0 + c * 32, sBhi + c * 4096 + wofs);
        }
        if (TWOPASS) {
            #pragma unroll
            for (int c = 0; c < NCH; ++c)
                gl_lds16(gBl + k0 + c * 32, sBlo + c * 4096 + wofs);
        }
        __syncthreads();
        #pragma unroll
        for (int h = 0; h < NCH; ++h) {
            const int ho = h * 4096;
            bf16x8 ah[2], bh[2];
            #pragma unroll
            for (int i = 0; i < 2; ++i) {
                ah[i] = *(const bf16x8*)(sA + ho + aoff[i]);
                bh[i] = *(const bf16x8*)(sBhi + ho + boff[i]);
            }
            #pragma unroll
            for (int mi = 0; mi < 2; ++mi)
                #pragma unroll
                for (int ni = 0; ni < 2; ++ni)
                    acc[mi][ni] = __builtin_amdgcn_mfma_f32_16x16x32_bf16(ah[mi], bh[ni], acc[mi][ni], 0, 0, 0);
            if (TWOPASS) {
                bf16x8 bl[2];
                #pragma unroll
                for (int i = 0; i < 2; ++i) bl[i] = *(const bf16x8*)(sBlo + ho + boff[i]);
                #pragma unroll
                for (int mi = 0; mi < 2; ++mi)
                    #pragma unroll
                    for (int ni = 0; ni < 2; ++ni)
                        acc[mi][ni] = __builtin_amdgcn_mfma_f32_16x16x32_bf16(ah[mi], bl[ni], acc[mi][ni], 0, 0, 0);
            }
        }
        __syncthreads();
    }

    int cc[2]; float bv[2];
    #pragma unroll
    for (int ni = 0; ni < 2; ++ni) {
        cc[ni] = col0 + wc * 32 + ni * 16 + r16;
        bv[ni] = bias[cc[ni]];
    }
    if (MODE == 0) {
        unsigned short* CE = Cout + (size_t)e * M * N;
        #pragma unroll
        for (int mi = 0; mi < 2; ++mi) {
            int rb = row0 + wr * 32 + mi * 16 + quad * 4;
            #pragma unroll
            for (int reg = 0; reg < 4; ++reg) {
                size_t roff = (size_t)(rb + reg) * N;
                #pragma unroll
                for (int ni = 0; ni < 2; ++ni)
                    CE[roff + cc[ni]] = f2b(gelu_f(acc[mi][ni][reg] + bv[ni]));
            }
        }
    } else {
        #pragma unroll
        for (int mi = 0; mi < 2; ++mi) {
            int rb = row0 + wr * 32 + mi * 16 + quad * 4;
            #pragma unroll
            for (int reg = 0; reg < 4; ++reg) {
                int i = rb + reg;
                if (i < cn) {
                    int tok = listG[e * NTOK + i];
                    float g = gates[(size_t)tok * Ee + e];
                    size_t roff = ((size_t)e * NTOK + i) * N;
                    #pragma unroll
                    for (int ni = 0; ni < 2; ++ni)
                        outf[roff + cc[ni]] = g * (acc[mi][ni][reg] + bv[ni]);
                }
            }
        }
    }
}

// ============================================================================
// gemm_sp128x64: 128x64 tile, 4 waves (2x2), wave-tile 64x32, acc[4][2],
// BK=128, LDS 48KB (A 32K | B 16K) -> 3 blocks/CU; grid (16, <=39) ~ 624
// blocks ~ 2.4 resident/CU. MFMA:ds_read density 1.33 vs 1.0 at 64^2.
// A-side 128-row staging/fragments lifted from R5's harness-passed gemm_sp128.
// MODE 0 (gemm2): gelu -> bf16 compact. MODE 1 (gemm3): gated fp32 store.
// ============================================================================
template<int MODE>
__global__ __launch_bounds__(256, 3) void gemm_sp128x64(
    const unsigned short* __restrict__ AG,
    const unsigned short* __restrict__ BG,
    const float* __restrict__ biasG, const float* __restrict__ gates,
    const int* __restrict__ cntG, const int* __restrict__ listG,
    unsigned short* __restrict__ Cout, float* __restrict__ outf,
    int M, int N, int K)
{
    // derive (expert, row-tile) from cnt prefix (128-row tiles)
    int m = blockIdx.y, e;
    #pragma unroll
    for (e = 0; e < Ee; ++e) {
        int te = (cntG[e] + 127) >> 7;
        if (m < te) break;
        m -= te;
    }
    if (e == Ee) return;
    const int row0 = m * 128;
    const int cn = cntG[e];

    __shared__ char smem[49152];                  // A 4x8K | B 4x4K
    char* sA = smem;
    char* sB = smem + 32768;

    const unsigned short* B = BG + (size_t)e * N * K;
    const float* bias = biasG + (size_t)e * N;

    const int t = threadIdx.x;
    const int lane = t & 63, w = t >> 6;
    const int r16 = lane & 15, quad = lane >> 4;
    const int wr = w >> 1, wc = w & 1;
    const int col0 = blockIdx.x * 64;

    // frag offsets within one [128r x 32c] A-chunk (8192B) / [64r x 32c] B-chunk
    int aoff[4], boff[2];
    #pragma unroll
    for (int i = 0; i < 4; ++i) {
        int ra = wr * 64 + i * 16 + r16;
        aoff[i] = ra * 64 + ((quad ^ ((ra >> 1) & 3)) << 4);
    }
    #pragma unroll
    for (int i = 0; i < 2; ++i) {
        int rb = wc * 32 + i * 16 + r16;
        boff[i] = rb * 64 + ((quad ^ ((rb >> 1) & 3)) << 4);
    }

    // staging: thread t covers row r0s of each 64-row half, pre-swizzled col
    const int r0s = t >> 2, c0s = ((t & 3) ^ ((r0s >> 1) & 3)) << 3;
    int ri0 = row0 + r0s;       if (ri0 > cn - 1) ri0 = cn - 1;
    int ri1 = row0 + 64 + r0s;  if (ri1 > cn - 1) ri1 = cn - 1;
    const unsigned short* gA0 = AG + ((size_t)e * M + ri0) * K + c0s;
    const unsigned short* gA1 = AG + ((size_t)e * M + ri1) * K + c0s;
    const unsigned short* gB0 = B + (size_t)(col0 + r0s) * K + c0s;
    const int wofs = w << 10;

    f32x4 acc[4][2];
    const f32x4 zero4 = {0.f, 0.f, 0.f, 0.f};
    #pragma unroll
    for (int i = 0; i < 4; ++i)
        #pragma unroll
        for (int j = 0; j < 2; ++j) acc[i][j] = zero4;

    for (int k0 = 0; k0 < K; k0 += 128) {
        #pragma unroll
        for (int c = 0; c < 4; ++c) {
            int kc = k0 + c * 32;
            gl_lds16(gA0 + kc, sA + c * 8192 + wofs);
            gl_lds16(gA1 + kc, sA + c * 8192 + 4096 + wofs);
            gl_lds16(gB0 + kc, sB + c * 4096 + wofs);
        }
        __syncthreads();
        #pragma unroll
        for (int h = 0; h < 4; ++h) {
            const int hoA = h * 8192, hoB = h * 4096;
            bf16x8 a[4], b2[2];
            #pragma unroll
            for (int i = 0; i < 4; ++i)
                a[i] = *(const bf16x8*)(sA + hoA + aoff[i]);
            #pragma unroll
            for (int i = 0; i < 2; ++i)
                b2[i] = *(const bf16x8*)(sB + hoB + boff[i]);
            #pragma unroll
            for (int mi = 0; mi < 4; ++mi)
                #pragma unroll
                for (int ni = 0; ni < 2; ++ni)
                    acc[mi][ni] = __builtin_amdgcn_mfma_f32_16x16x32_bf16(a[mi], b2[ni], acc[mi][ni], 0, 0, 0);
        }
        __syncthreads();
    }

    int cc[2]; float bv[2];
    #pragma unroll
    for (int ni = 0; ni < 2; ++ni) {
        cc[ni] = col0 + wc * 32 + ni * 16 + r16;
        bv[ni] = bias[cc[ni]];
    }
    if (MODE == 0) {
        unsigned short* CE = Cout + (size_t)e * M * N;
        #pragma unroll
        for (int mi = 0; mi < 4; ++mi) {
            int rb = row0 + wr * 64 + mi * 16 + quad * 4;
            #pragma unroll
            for (int reg = 0; reg < 4; ++reg) {
                size_t roff = (size_t)(rb + reg) * N;
                #pragma unroll
                for (int ni = 0; ni < 2; ++ni)
                    CE[roff + cc[ni]] = f2b(gelu_f(acc[mi][ni][reg] + bv[ni]));
            }
        }
    } else {
        #pragma unroll
        for (int mi = 0; mi < 4; ++mi) {
            int rb = row0 + wr * 64 + mi * 16 + quad * 4;
            #pragma unroll
            for (int reg = 0; reg < 4; ++reg) {
                int i = rb + reg;
                if (i < cn) {
                    int tok = listG[e * NTOK + i];
                    float g = gates[(size_t)tok * Ee + e];
                    size_t roff = ((size_t)e * NTOK + i) * N;
                    #pragma unroll
                    for (int ni = 0; ni < 2; ++ni)
                        outf[roff + cc[ni]] = g * (acc[mi][ni][reg] + bv[ni]);
                }
            }
        }
    }
}

// ============================ router tail ==============================

// gates_topk: grid-parallel (8 blocks x 256 thr = 1 thr/token).
__global__ __launch_bounds__(256) void gates_topk(const float* __restrict__ logits,
                                                  const float* __restrict__ fl_b,
                                                  float* __restrict__ gates,
                                                  int* __restrict__ cnt,
                                                  int* __restrict__ list,
                                                  int* __restrict__ rowidx) {
    const int tok = blockIdx.x * 256 + threadIdx.x;
    const int lane = threadIdx.x & 63;
    const unsigned long long ltmask = (1ull << lane) - 1ull;

    float s[Ee];
    #pragma unroll
    for (int e = 0; e < Ee; ++e) {
        float z = logits[tok * Ee + e] + fl_b[e];
        s[e] = 1.0f / (1.0f + expf(-z));
    }
    float mx = s[0];
    #pragma unroll
    for (int e = 1; e < Ee; ++e) mx = fmaxf(mx, s[e]);
    float p[Ee];
    #pragma unroll
    for (int e = 0; e < Ee; ++e) p[e] = expf(s[e] - mx);
    int i1 = 0;
    #pragma unroll
    for (int e = 1; e < Ee; ++e) if (p[e] > p[i1]) i1 = e;
    int i2 = (i1 == 0) ? 1 : 0;
    #pragma unroll
    for (int e = 0; e < Ee; ++e) {
        if (e == i1 || e == i2) continue;
        if (p[e] > p[i2]) i2 = e;
    }
    float inv = 1.0f / (p[i1] + p[i2]);
    #pragma unroll
    for (int e = 0; e < Ee; ++e) gates[tok * Ee + e] = 0.0f;
    gates[tok * Ee + i1] = p[i1] * inv;
    gates[tok * Ee + i2] = p[i2] * inv;

    #pragma unroll
    for (int slot = 0; slot < 2; ++slot) {
        int ie = slot ? i2 : i1;
        for (int e = 0; e < Ee; ++e) {
            unsigned long long m = __ballot(ie == e);
            if (m) {
                int leader = __ffsll((long long)m) - 1;
                int base = 0;
                if (lane == leader) base = atomicAdd(&cnt[e], (int)__popcll(m));
                base = __shfl(base, leader);
                if (ie == e) {
                    int pos = base + (int)__popcll(m & ltmask);
                    list[e * NTOK + pos] = tok;
                    rowidx[tok * 2 + slot] = e * NTOK + pos;
                }
            }
        }
    }
}

// combine_out: out[b][o][d] = h3g[r0][o] + h3g[r1][o]  (rows pre-gated)
__global__ __launch_bounds__(256) void combine_out(const float* __restrict__ h3g,
                                                   const int* __restrict__ rowidx,
                                                   float* __restrict__ out) {
    __shared__ float tile[32][33];
    int b = blockIdx.z;
    int d0 = blockIdx.x * 32;
    int o0 = blockIdx.y * 32;
    int tx = threadIdx.x & 31, ty = threadIdx.x >> 5;
    for (int i = 0; i < 32; i += 8) {
        int tok = b * Dd + d0 + ty + i;
        int r0 = rowidx[tok * 2];
        int r1 = rowidx[tok * 2 + 1];
        tile[ty + i][tx] = h3g[(size_t)r0 * Hh + o0 + tx] + h3g[(size_t)r1 * Hh + o0 + tx];
    }
    __syncthreads();
    for (int i = 0; i < 32; i += 8)
        out[((size_t)b * Hh + o0 + ty + i) * Dd + d0 + tx] = tile[tx][ty + i];
}

extern "C" void kernel_launch(void* const* d_in, const int* in_sizes, int n_in,
                              void* d_out, int out_size, void* d_ws, size_t ws_size,
                              hipStream_t stream) {
    const float* x       = (const float*)d_in[0];
    const float* conv_w  = (const float*)d_in[1];
    const float* conv_b  = (const float*)d_in[2];
    const float* fl_w    = (const float*)d_in[3];
    const float* fl_b    = (const float*)d_in[4];
    const float* w1      = (const float*)d_in[5];
    const float* b1      = (const float*)d_in[6];
    const float* w2      = (const float*)d_in[7];
    const float* b2      = (const float*)d_in[8];
    const float* w3      = (const float*)d_in[9];
    const float* b3      = (const float*)d_in[10];
    float* out = (float*)d_out;

    char* ws = (char*)d_ws;
    // Workspace map (peak ~128.3 MB):
    //  phase A (conv): xphi/xplo/cphi/cplo/wchi/wclo @ 0..19.3MB, xe @67.1MB
    //  phase B: h1 @0 (33.5MB) | h2 @67.1MB (33.5MB)
    //  phase C: h3g @0 (67.1MB, over dead h1)
    unsigned short* xphi = (unsigned short*)(ws);
    unsigned short* xplo = (unsigned short*)(ws + 4227072);
    unsigned short* cphi = (unsigned short*)(ws + 8454144);
    unsigned short* cplo = (unsigned short*)(ws + 12681216);
    unsigned short* wchi = (unsigned short*)(ws + 16908288);
    unsigned short* wclo = (unsigned short*)(ws + 18087936);
    unsigned short* h1   = (unsigned short*)(ws);                 // 33.5 MB
    unsigned short* h2   = (unsigned short*)(ws + 67108864);      // 33.5 MB
    float*          h3g  = (float*)(ws);                          // 67.1 MB
    unsigned short* xe   = (unsigned short*)(ws + 67108864);      // 16.8 MB (phase A/B1)
    unsigned short* w1hi = (unsigned short*)(ws + 83886080);
    unsigned short* w1lo = (unsigned short*)(ws + 92274688);
    unsigned short* w2b  = (unsigned short*)(ws + 100663296);
    unsigned short* w3b  = (unsigned short*)(ws + 117440512);
    float* logits  = (float*)(ws + 134217728);
    int*   cnt     = (int*)(ws + 134283264);
    float* gates   = (float*)(ws + 134284288);
    int*   list    = (int*)(ws + 134349824);
    int*   rowidx  = (int*)(ws + 134415360);     // 16 KB

    // prep: padzero + x-split + conv-w split + logits/cnt zero (593 blocks)
    prep_all<<<593, 256, 0, stream>>>(x, conv_w, xphi, xplo, cphi, cplo,
                                      wchi, wclo, logits);

    // Router convs on MFMA (64x64 tiles, 4 blocks/CU). Extra grid rows:
    //   conv1: rows [4,8) = w1 cvt (512); rows [8,40) = downsample (4096)
    //   conv2: rows [4,12) = w2 cvt (1024)
    //   conv3: rows [4,12) = w3 cvt (1024)
    const int WL = 3 * Dd * Dd;
    conv_mfma<0, 1, 4, 1><<<dim3(Bb * Ll / 64, Dd / 64 + 4 + 32), 256, 0, stream>>>(
        xphi, xplo, wchi + 0 * WL, wclo + 0 * WL, conv_b + 0 * Dd, cphi, cplo,
        nullptr, nullptr, w1, w1hi, w1lo, x, xe, 1);
    conv_mfma<0, 2, 8, 0><<<dim3(Bb * Ll / 64, Dd / 64 + 8), 256, 0, stream>>>(
        cphi, cplo, wchi + 1 * WL, wclo + 1 * WL, conv_b + 1 * Dd, xphi, xplo,
        nullptr, nullptr, w2, w2b, nullptr, nullptr, nullptr, 2);
    conv_mfma<1, 2, 8, 0><<<dim3(Bb * Ll / 64, Dd / 64 + 8), 256, 0, stream>>>(
        xphi, xplo, wchi + 2 * WL, wclo + 2 * WL, conv_b + 2 * Dd, nullptr, nullptr,
        fl_w, logits, w3, w3b, nullptr, nullptr, nullptr, 4);

    // grid-parallel router tail
    gates_topk<<<NTOK / 256, 256, 0, stream>>>(logits, fl_b, gates, cnt, list, rowidx);

    // GEMM1 sparse (gathered A from xe, per-expert K-cap, w1 split 2-pass, 64^2)
    gemm_sp<0, 1, 1><<<dim3(16, MAXTILES), 256, 0, stream>>>(
        xe, w1hi, w1lo, b1, nullptr, cnt, list, h1, nullptr, NTOK, Hh, LMAXc);

    // GEMM2 sparse (compact->compact, K=1024, 128x64 high-density tiles)
    gemm_sp128x64<0><<<dim3(16, MAXT128), 256, 0, stream>>>(
        h1, w2b, b2, nullptr, cnt, list, h2, nullptr, NTOK, Hh, Hh);

    // GEMM3 sparse (compact A, 128x64 tiles, gated fp32 store — NO atomics)
    gemm_sp128x64<1><<<dim3(16, MAXT128), 256, 0, stream>>>(
        h2, w3b, b3, gates, cnt, list, nullptr, h3g, NTOK, Hh, Hh);

    // gather 2 gated rows per token, sum, write transposed output
    combine_out<<<dim3(Dd / 32, Hh / 32, Bb), 256, 0, stream>>>(h3g, rowidx, out);
}

// Round 18
// 286.417 us; speedup vs baseline: 1.0062x; 1.0062x over previous
//
#include <hip/hip_runtime.h>
#include <math.h>

#define Bb 8
#define Ll 1024
#define Dd 256
#define Ee 8
#define Hh 1024
#define LMAXc 512
#define NTOK (Bb*Dd)   // 2048
#define LPAD 1032      // 4 + 1024 + 4 padded token rows per batch
#define MAXTILES 72    // worst-case sum_e ceil(cnt[e]/64): 4096/64 + 7

typedef short bf16x8 __attribute__((ext_vector_type(8)));
typedef float f32x4 __attribute__((ext_vector_type(4)));
typedef unsigned short u16x8 __attribute__((ext_vector_type(8)));

__device__ __forceinline__ float gelu_f(float x) {
    return 0.5f * x * (1.0f + erff(x * 0.70710678118654752440f));
}
__device__ __forceinline__ unsigned short f2b(float x) {          // RTN fp32->bf16
    unsigned int u = __float_as_uint(x);
    return (unsigned short)((u + 0x7fffu + ((u >> 16) & 1u)) >> 16);
}
__device__ __forceinline__ float b2f(unsigned short h) {
    return __uint_as_float(((unsigned int)h) << 16);
}
__device__ __forceinline__ void gl_lds16(const void* g, void* l) {
    __builtin_amdgcn_global_load_lds((const __attribute__((address_space(1))) unsigned int*)g,
                                     (__attribute__((address_space(3))) unsigned int*)l, 16, 0, 0);
}

// ============================================================================
// prep_all v4: ONLY what conv1 needs + logits zeroing. Downsample rides
// conv1's grid; memset folded in here.
//   [0,32)     : zero pad rows of xphi/xplo/cphi/cplo
//   [32,288)   : pad+split x -> [B][LPAD][D] bf16 hi/lo planes (oct, ILP4)
//   [288,576)  : conv weights [3][D][D][3] -> split planes
//   [576,593)  : zero logits (65536 B) + cnt (64 B)
// ============================================================================
__global__ __launch_bounds__(256) void prep_all(
    const float* __restrict__ x, const float* __restrict__ cw,
    unsigned short* __restrict__ xhi, unsigned short* __restrict__ xlo,
    unsigned short* __restrict__ chi, unsigned short* __restrict__ clo,
    unsigned short* __restrict__ wchi, unsigned short* __restrict__ wclo,
    float* __restrict__ zbase)
{
    int blk = blockIdx.x;
    int t = threadIdx.x;
    if (blk < 32) {
        // zero pad rows: 4 buffers x (8 batches x 8 rows x 256 elems)
        int u = blk * 256 + t;                     // [0, 8192)
        int f = u >> 11;
        int rem = u & 2047;
        int b = rem >> 8;
        int r2 = rem & 255;
        int row = r2 >> 5;
        int col = (r2 & 31) * 8;
        int padrow = (row < 4) ? row : (1024 + row);
        unsigned short* buf = (f == 0) ? xhi : (f == 1) ? xlo : (f == 2) ? chi : clo;
        u16x8 z = {0, 0, 0, 0, 0, 0, 0, 0};
        *(u16x8*)(buf + (size_t)(b * LPAD + padrow) * Dd + col) = z;
    } else if (blk < 288) {
        // x split: 262144 octs (8 floats), ILP4, 16B hi + 16B lo stores
        int cb = blk - 32;
        const float4* s4 = (const float4*)x;
        size_t ob = (size_t)cb * 1024 + t;
        float4 v[8];
        #pragma unroll
        for (int it = 0; it < 4; ++it) {
            v[2 * it]     = s4[(ob + it * 256) * 2];
            v[2 * it + 1] = s4[(ob + it * 256) * 2 + 1];
        }
        #pragma unroll
        for (int it = 0; it < 4; ++it) {
            size_t o = ob + it * 256;
            int d8 = (int)(o & 31), l = (int)((o >> 5) & 1023), b = (int)(o >> 15);
            size_t ooff = (size_t)(b * LPAD + 4 + l) * Dd + d8 * 8;
            float vv[8] = {v[2*it].x, v[2*it].y, v[2*it].z, v[2*it].w,
                           v[2*it+1].x, v[2*it+1].y, v[2*it+1].z, v[2*it+1].w};
            u16x8 hv, lv;
            #pragma unroll
            for (int q = 0; q < 8; ++q) {
                unsigned short h = f2b(vv[q]);
                hv[q] = (short)h;
                lv[q] = (short)f2b(vv[q] - b2f(h));
            }
            *(u16x8*)(xhi + ooff) = hv;
            *(u16x8*)(xlo + ooff) = lv;
        }
    } else if (blk < 576) {
        // conv weights: 589824 outputs; thread = 8 consecutive outputs
        int cb = blk - 288;                        // [0, 288)
        int idx0 = (cb * 256 + t) * 8;
        float vv[8];
        #pragma unroll
        for (int q = 0; q < 8; ++q) {
            int idx = idx0 + q;
            int i = idx & (Dd - 1);
            int o = (idx >> 8) & (Dd - 1);
            int lk = idx >> 16;
            int layer = lk / 3;
            int k = lk % 3;
            vv[q] = cw[(((size_t)layer * Dd + o) * Dd + i) * 3 + k];
        }
        u16x8 hv, lv;
        #pragma unroll
        for (int q = 0; q < 8; ++q) {
            unsigned short h = f2b(vv[q]);
            hv[q] = (short)h;
            lv[q] = (short)f2b(vv[q] - b2f(h));
        }
        *(u16x8*)(wchi + idx0) = hv;
        *(u16x8*)(wclo + idx0) = lv;
    } else {
        // zero logits (65536 B) + cnt (64 B) = 4100 x 16B
        int idx = (blk - 576) * 256 + t;
        if (idx < 4100) {
            u16x8 z = {0, 0, 0, 0, 0, 0, 0, 0};
            *(u16x8*)((char*)zbase + (size_t)idx * 16) = z;
        }
    }
}

// ============================================================================
// conv_mfma (R12 structure, 4 blocks/CU): dilated conv as MFMA NT-GEMM,
// 3-pass split, 64x64 tile, 4 waves (2x2 of 32x32), BK=64.
// MODE 0: split hi/lo output planes.  MODE 1: fused router-logits epilogue.
// CVT rows [4, 4+NCVT): stream fp32 expert weights -> bf16 planes.
// DS=1 (conv1 only): downsample x -> xe rides the CU slack.
// ============================================================================
template<int MODE, int CVT, int NCVT, int DS>
__global__ __launch_bounds__(256, 4) void conv_mfma(
    const unsigned short* __restrict__ inhi, const unsigned short* __restrict__ inlo,
    const unsigned short* __restrict__ whiL, const unsigned short* __restrict__ wloL,
    const float* __restrict__ bias,
    unsigned short* __restrict__ outhi, unsigned short* __restrict__ outlo,
    const float* __restrict__ flw, float* __restrict__ logits,
    const float* __restrict__ cvsrc, unsigned short* __restrict__ cvd1,
    unsigned short* __restrict__ cvd2,
    const float* __restrict__ dsx, unsigned short* __restrict__ dsxe, int dil)
{
    __shared__ char smem[32768];

    if (DS && blockIdx.y >= (Dd / 64) + NCVT) {
        // downsample: u = (e*8 + b)*64 + c;  j0 = c*8; threads = d
        int u = (blockIdx.y - (Dd / 64) - NCVT) * 128 + blockIdx.x;  // [0,4096)
        int e = u >> 9;
        int b = (u >> 6) & 7;
        int c = u & 63;
        int f = e + 2;
        int Li = Ll / f;
        int j0 = c * 8;
        if (j0 >= Li) return;
        int d = threadIdx.x;
        float invf = 1.0f / (float)f;
        int lim = Li - 1;
        float v[8] = {};
        for (int r = 0; r < f; ++r) {
            #pragma unroll
            for (int jj = 0; jj < 8; ++jj) {
                int j = j0 + jj; if (j > lim) j = lim;
                v[jj] += dsx[((size_t)(b * Ll + j * f + r)) * Dd + d];
            }
        }
        size_t obase = ((size_t)(e * NTOK + b * 256 + d)) * LMAXc + j0;
        if (j0 + 8 <= Li) {
            u16x8 hv;
            #pragma unroll
            for (int q = 0; q < 8; ++q) hv[q] = (short)f2b(v[q] * invf);
            *(u16x8*)(dsxe + obase) = hv;
        } else {
            for (int jj = 0; jj < Li - j0; ++jj)
                dsxe[obase + jj] = f2b(v[jj] * invf);
        }
        return;
    }

    if (CVT && blockIdx.y >= (Dd / 64)) {
        int cb = (blockIdx.y - Dd / 64) * 128 + blockIdx.x;
        int t = threadIdx.x;
        const float4* s4 = (const float4*)cvsrc;
        size_t ob = (size_t)cb * 1024 + t;
        float4 v[8];
        #pragma unroll
        for (int it = 0; it < 4; ++it) {
            v[2 * it]     = s4[(ob + it * 256) * 2];
            v[2 * it + 1] = s4[(ob + it * 256) * 2 + 1];
        }
        #pragma unroll
        for (int it = 0; it < 4; ++it) {
            size_t o = ob + it * 256;
            float vv[8] = {v[2*it].x, v[2*it].y, v[2*it].z, v[2*it].w,
                           v[2*it+1].x, v[2*it+1].y, v[2*it+1].z, v[2*it+1].w};
            u16x8 hv, lv;
            #pragma unroll
            for (int q = 0; q < 8; ++q) {
                unsigned short h = f2b(vv[q]);
                hv[q] = (short)h;
                if (CVT == 1) lv[q] = (short)f2b(vv[q] - b2f(h));
            }
            *(u16x8*)(cvd1 + o * 8) = hv;
            if (CVT == 1) *(u16x8*)(cvd2 + o * 8) = lv;
        }
        return;
    }

    char* sAhi = smem;
    char* sAlo = smem + 8192;
    char* sBhi = smem + 16384;
    char* sBlo = smem + 24576;

    const int t = threadIdx.x;
    const int lane = t & 63, w = t >> 6;
    const int r16 = lane & 15, quad = lane >> 4;
    const int wr = w >> 1, wc = w & 1;
    const int row0 = blockIdx.x * 64;
    const int col0 = blockIdx.y * 64;
    const int b = row0 >> 10, l0 = row0 & 1023;

    int aoff[2], boff[2];
    #pragma unroll
    for (int i = 0; i < 2; ++i) {
        int ra = wr * 32 + i * 16 + r16;
        aoff[i] = ra * 64 + ((quad ^ ((ra >> 1) & 3)) << 4);
        int rb = wc * 32 + i * 16 + r16;
        boff[i] = rb * 64 + ((quad ^ ((rb >> 1) & 3)) << 4);
    }
    const int rs = t >> 2, ce = ((t & 3) ^ ((rs >> 1) & 3)) << 3;
    const unsigned short* gAhi = inhi + (size_t)(b * LPAD + 4 + l0 + rs) * Dd + ce;
    const unsigned short* gAlo = inlo + (size_t)(b * LPAD + 4 + l0 + rs) * Dd + ce;

    f32x4 acc[2][2];
    const f32x4 zero4 = {0.f, 0.f, 0.f, 0.f};
    #pragma unroll
    for (int i = 0; i < 2; ++i)
        #pragma unroll
        for (int j = 0; j < 2; ++j) acc[i][j] = zero4;

    for (int tap = 0; tap < 3; ++tap) {
        const int sh = (tap - 1) * dil;
        const unsigned short* pAhi = gAhi + sh * Dd;
        const unsigned short* pAlo = gAlo + sh * Dd;
        const unsigned short* gBhi = whiL + ((size_t)tap * Dd + col0 + rs) * Dd + ce;
        const unsigned short* gBlo = wloL + ((size_t)tap * Dd + col0 + rs) * Dd + ce;
        for (int kb = 0; kb < Dd; kb += 64) {
            gl_lds16(pAhi + kb,      sAhi + (w << 10));
            gl_lds16(pAhi + kb + 32, sAhi + 4096 + (w << 10));
            gl_lds16(pAlo + kb,      sAlo + (w << 10));
            gl_lds16(pAlo + kb + 32, sAlo + 4096 + (w << 10));
            gl_lds16(gBhi + kb,      sBhi + (w << 10));
            gl_lds16(gBhi + kb + 32, sBhi + 4096 + (w << 10));
            gl_lds16(gBlo + kb,      sBlo + (w << 10));
            gl_lds16(gBlo + kb + 32, sBlo + 4096 + (w << 10));
            __syncthreads();
            #pragma unroll
            for (int h = 0; h < 2; ++h) {
                const int ho = h * 4096;
                bf16x8 ah[2], al[2], bh[2], bl[2];
                #pragma unroll
                for (int i = 0; i < 2; ++i) {
                    ah[i] = *(const bf16x8*)(sAhi + ho + aoff[i]);
                    al[i] = *(const bf16x8*)(sAlo + ho + aoff[i]);
                    bh[i] = *(const bf16x8*)(sBhi + ho + boff[i]);
                    bl[i] = *(const bf16x8*)(sBlo + ho + boff[i]);
                }
                #pragma unroll
                for (int mi = 0; mi < 2; ++mi)
                    #pragma unroll
                    for (int ni = 0; ni < 2; ++ni) {
                        acc[mi][ni] = __builtin_amdgcn_mfma_f32_16x16x32_bf16(ah[mi], bh[ni], acc[mi][ni], 0, 0, 0);
                        acc[mi][ni] = __builtin_amdgcn_mfma_f32_16x16x32_bf16(ah[mi], bl[ni], acc[mi][ni], 0, 0, 0);
                        acc[mi][ni] = __builtin_amdgcn_mfma_f32_16x16x32_bf16(al[mi], bh[ni], acc[mi][ni], 0, 0, 0);
                    }
            }
            __syncthreads();
        }
    }

    int cc[2]; float bv[2];
    #pragma unroll
    for (int ni = 0; ni < 2; ++ni) {
        cc[ni] = col0 + wc * 32 + ni * 16 + r16;
        bv[ni] = bias[cc[ni]];
    }
    if (MODE == 0) {
        #pragma unroll
        for (int mi = 0; mi < 2; ++mi) {
            int lb = l0 + wr * 32 + mi * 16 + quad * 4;
            #pragma unroll
            for (int reg = 0; reg < 4; ++reg) {
                int l = lb + reg;
                #pragma unroll
                for (int ni = 0; ni < 2; ++ni) {
                    float v = gelu_f(acc[mi][ni][reg] + bv[ni]);
                    size_t o = (size_t)(b * LPAD + 4 + l) * Dd + cc[ni];
                    unsigned short h = f2b(v);
                    outhi[o] = h;
                    outlo[o] = f2b(v - b2f(h));
                }
            }
        }
    } else {
        // fused logits: LDS partials over the 64x64 tile, then 512 atomics.
        float* wl   = (float*)smem;            // [64 l_local][8 e]
        float* slog = (float*)(smem + 2048);   // [64 d_local][8 e]
        for (int i = t; i < 512; i += 256) {
            int ll = i >> 3, e = i & 7;
            wl[i] = flw[e * Ll + l0 + ll];
            slog[i] = 0.0f;
        }
        __syncthreads();
        float part[2][8];
        #pragma unroll
        for (int ni = 0; ni < 2; ++ni)
            #pragma unroll
            for (int e = 0; e < 8; ++e) part[ni][e] = 0.0f;
        #pragma unroll
        for (int mi = 0; mi < 2; ++mi) {
            #pragma unroll
            for (int reg = 0; reg < 4; ++reg) {
                int ll = wr * 32 + mi * 16 + quad * 4 + reg;
                #pragma unroll
                for (int ni = 0; ni < 2; ++ni) {
                    float v = gelu_f(acc[mi][ni][reg] + bv[ni]);
                    #pragma unroll
                    for (int e = 0; e < 8; ++e) part[ni][e] += v * wl[ll * 8 + e];
                }
            }
        }
        #pragma unroll
        for (int ni = 0; ni < 2; ++ni) {
            int dl = wc * 32 + ni * 16 + r16;
            #pragma unroll
            for (int e = 0; e < 8; ++e) atomicAdd(&slog[dl * 8 + e], part[ni][e]);
        }
        __syncthreads();
        for (int i = t; i < 512; i += 256) {
            int dl = i >> 3, e = i & 7;
            atomicAdd(&logits[(size_t)(b * Dd + col0 + dl) * Ee + e], slog[i]);
        }
    }
}

// ============================================================================
// Sparse expert GEMM (64x64 tiles). Expert/tile derived inline from cnt[]
// prefix. MODE 0: gelu -> bf16 compact. MODE 1: gated fp32 store, no atomics.
// ============================================================================
template<int MODE, int GATHER, int TWOPASS>
__global__ __launch_bounds__(256, 4) void gemm_sp(
    const unsigned short* __restrict__ AG,
    const unsigned short* __restrict__ BhiG, const unsigned short* __restrict__ BloG,
    const float* __restrict__ biasG, const float* __restrict__ gates,
    const int* __restrict__ cntG, const int* __restrict__ listG,
    unsigned short* __restrict__ Cout, float* __restrict__ outf,
    int M, int N, int K)
{
    // derive (expert, row-tile) from cnt prefix — uniform across the block
    int m = blockIdx.y, e;
    #pragma unroll
    for (e = 0; e < Ee; ++e) {
        int te = (cntG[e] + 63) >> 6;
        if (m < te) break;
        m -= te;
    }
    if (e == Ee) return;
    const int row0 = m * 64;
    const int cn = cntG[e];

    constexpr int NCH = TWOPASS ? 2 : 4;          // 32-col chunks per K-iter
    __shared__ char smem[TWOPASS ? 24576 : 32768];
    char* sA   = smem;
    char* sBhi = smem + NCH * 4096;
    char* sBlo = smem + 2 * NCH * 4096;           // TWOPASS only

    const unsigned short* Bhi = BhiG + (size_t)e * N * K;
    const unsigned short* Blo = TWOPASS ? (BloG + (size_t)e * N * K) : nullptr;
    const float* bias = biasG + (size_t)e * N;

    int Keff = K;
    if (GATHER) {
        int Li = Ll / (e + 2);
        Keff = ((Li + 63) >> 6) << 6;
    }

    const int t = threadIdx.x;
    const int lane = t & 63, w = t >> 6;
    const int r16 = lane & 15, quad = lane >> 4;
    const int wr = w >> 1, wc = w & 1;
    const int col0 = blockIdx.x * 64;

    int aoff[2], boff[2];
    #pragma unroll
    for (int i = 0; i < 2; ++i) {
        int ra = wr * 32 + i * 16 + r16;
        aoff[i] = ra * 64 + ((quad ^ ((ra >> 1) & 3)) << 4);
        int rb = wc * 32 + i * 16 + r16;
        boff[i] = rb * 64 + ((quad ^ ((rb >> 1) & 3)) << 4);
    }
    const int r0s = t >> 2, c0s = ((t & 3) ^ ((r0s >> 1) & 3)) << 3;
    int ri = row0 + r0s; if (ri > cn - 1) ri = cn - 1;
    const int ar = GATHER ? listG[e * NTOK + ri] : ri;
    const unsigned short* gA  = AG + ((size_t)e * M + ar) * K + c0s;
    const unsigned short* gB  = Bhi + (size_t)(col0 + r0s) * K + c0s;
    const unsigned short* gBl = TWOPASS ? (Blo + (size_t)(col0 + r0s) * K + c0s) : nullptr;
    const int wofs = w << 10;

    f32x4 acc[2][2];
    const f32x4 zero4 = {0.f, 0.f, 0.f, 0.f};
    #pragma unroll
    for (int i = 0; i < 2; ++i)
        #pragma unroll
        for (int j = 0; j < 2; ++j) acc[i][j] = zero4;

    for (int k0 = 0; k0 < Keff; k0 += NCH * 32) {
        #pragma unroll
        for (int c = 0; c < NCH; ++c) {
            gl_lds16(gA + k0 + c * 32, sA + c * 4096 + wofs);
            gl_lds16(gB + k0 + c * 32, sBhi + c * 4096 + wofs);
        }
        if (TWOPASS) {
            #pragma unroll
            for (int c = 0; c < NCH; ++c)
                gl_lds16(gBl + k0 + c * 32, sBlo + c * 4096 + wofs);
        }
        __syncthreads();
        #pragma unroll
        for (int h = 0; h < NCH; ++h) {
            const int ho = h * 4096;
            bf16x8 ah[2], bh[2];
            #pragma unroll
            for (int i = 0; i < 2; ++i) {
                ah[i] = *(const bf16x8*)(sA + ho + aoff[i]);
                bh[i] = *(const bf16x8*)(sBhi + ho + boff[i]);
            }
            #pragma unroll
            for (int mi = 0; mi < 2; ++mi)
                #pragma unroll
                for (int ni = 0; ni < 2; ++ni)
                    acc[mi][ni] = __builtin_amdgcn_mfma_f32_16x16x32_bf16(ah[mi], bh[ni], acc[mi][ni], 0, 0, 0);
            if (TWOPASS) {
                bf16x8 bl[2];
                #pragma unroll
                for (int i = 0; i < 2; ++i) bl[i] = *(const bf16x8*)(sBlo + ho + boff[i]);
                #pragma unroll
                for (int mi = 0; mi < 2; ++mi)
                    #pragma unroll
                    for (int ni = 0; ni < 2; ++ni)
                        acc[mi][ni] = __builtin_amdgcn_mfma_f32_16x16x32_bf16(ah[mi], bl[ni], acc[mi][ni], 0, 0, 0);
            }
        }
        __syncthreads();
    }

    int cc[2]; float bv[2];
    #pragma unroll
    for (int ni = 0; ni < 2; ++ni) {
        cc[ni] = col0 + wc * 32 + ni * 16 + r16;
        bv[ni] = bias[cc[ni]];
    }
    if (MODE == 0) {
        unsigned short* CE = Cout + (size_t)e * M * N;
        #pragma unroll
        for (int mi = 0; mi < 2; ++mi) {
            int rb = row0 + wr * 32 + mi * 16 + quad * 4;
            #pragma unroll
            for (int reg = 0; reg < 4; ++reg) {
                size_t roff = (size_t)(rb + reg) * N;
                #pragma unroll
                for (int ni = 0; ni < 2; ++ni)
                    CE[roff + cc[ni]] = f2b(gelu_f(acc[mi][ni][reg] + bv[ni]));
            }
        }
    } else {
        // gated plain-store epilogue: h3g row = e*NTOK + compact index
        #pragma unroll
        for (int mi = 0; mi < 2; ++mi) {
            int rb = row0 + wr * 32 + mi * 16 + quad * 4;
            #pragma unroll
            for (int reg = 0; reg < 4; ++reg) {
                int i = rb + reg;
                if (i < cn) {
                    int tok = listG[e * NTOK + i];
                    float g = gates[(size_t)tok * Ee + e];
                    size_t roff = ((size_t)e * NTOK + i) * N;
                    #pragma unroll
                    for (int ni = 0; ni < 2; ++ni)
                        outf[roff + cc[ni]] = g * (acc[mi][ni][reg] + bv[ni]);
                }
            }
        }
    }
}

// ============================ router tail ==============================

// gates_topk: grid-parallel (8 blocks x 256 thr = 1 thr/token).
__global__ __launch_bounds__(256) void gates_topk(const float* __restrict__ logits,
                                                  const float* __restrict__ fl_b,
                                                  float* __restrict__ gates,
                                                  int* __restrict__ cnt,
                                                  int* __restrict__ list,
                                                  int* __restrict__ rowidx) {
    const int tok = blockIdx.x * 256 + threadIdx.x;
    const int lane = threadIdx.x & 63;
    const unsigned long long ltmask = (1ull << lane) - 1ull;

    float s[Ee];
    #pragma unroll
    for (int e = 0; e < Ee; ++e) {
        float z = logits[tok * Ee + e] + fl_b[e];
        s[e] = 1.0f / (1.0f + expf(-z));
    }
    float mx = s[0];
    #pragma unroll
    for (int e = 1; e < Ee; ++e) mx = fmaxf(mx, s[e]);
    float p[Ee];
    #pragma unroll
    for (int e = 0; e < Ee; ++e) p[e] = expf(s[e] - mx);
    int i1 = 0;
    #pragma unroll
    for (int e = 1; e < Ee; ++e) if (p[e] > p[i1]) i1 = e;
    int i2 = (i1 == 0) ? 1 : 0;
    #pragma unroll
    for (int e = 0; e < Ee; ++e) {
        if (e == i1 || e == i2) continue;
        if (p[e] > p[i2]) i2 = e;
    }
    float inv = 1.0f / (p[i1] + p[i2]);
    #pragma unroll
    for (int e = 0; e < Ee; ++e) gates[tok * Ee + e] = 0.0f;
    gates[tok * Ee + i1] = p[i1] * inv;
    gates[tok * Ee + i2] = p[i2] * inv;

    #pragma unroll
    for (int slot = 0; slot < 2; ++slot) {
        int ie = slot ? i2 : i1;
        for (int e = 0; e < Ee; ++e) {
            unsigned long long m = __ballot(ie == e);
            if (m) {
                int leader = __ffsll((long long)m) - 1;
                int base = 0;
                if (lane == leader) base = atomicAdd(&cnt[e], (int)__popcll(m));
                base = __shfl(base, leader);
                if (ie == e) {
                    int pos = base + (int)__popcll(m & ltmask);
                    list[e * NTOK + pos] = tok;
                    rowidx[tok * 2 + slot] = e * NTOK + pos;
                }
            }
        }
    }
}

// combine_out: out[b][o][d] = h3g[r0][o] + h3g[r1][o]  (rows pre-gated)
__global__ __launch_bounds__(256) void combine_out(const float* __restrict__ h3g,
                                                   const int* __restrict__ rowidx,
                                                   float* __restrict__ out) {
    __shared__ float tile[32][33];
    int b = blockIdx.z;
    int d0 = blockIdx.x * 32;
    int o0 = blockIdx.y * 32;
    int tx = threadIdx.x & 31, ty = threadIdx.x >> 5;
    for (int i = 0; i < 32; i += 8) {
        int tok = b * Dd + d0 + ty + i;
        int r0 = rowidx[tok * 2];
        int r1 = rowidx[tok * 2 + 1];
        tile[ty + i][tx] = h3g[(size_t)r0 * Hh + o0 + tx] + h3g[(size_t)r1 * Hh + o0 + tx];
    }
    __syncthreads();
    for (int i = 0; i < 32; i += 8)
        out[((size_t)b * Hh + o0 + ty + i) * Dd + d0 + tx] = tile[tx][ty + i];
}

extern "C" void kernel_launch(void* const* d_in, const int* in_sizes, int n_in,
                              void* d_out, int out_size, void* d_ws, size_t ws_size,
                              hipStream_t stream) {
    const float* x       = (const float*)d_in[0];
    const float* conv_w  = (const float*)d_in[1];
    const float* conv_b  = (const float*)d_in[2];
    const float* fl_w    = (const float*)d_in[3];
    const float* fl_b    = (const float*)d_in[4];
    const float* w1      = (const float*)d_in[5];
    const float* b1      = (const float*)d_in[6];
    const float* w2      = (const float*)d_in[7];
    const float* b2      = (const float*)d_in[8];
    const float* w3      = (const float*)d_in[9];
    const float* b3      = (const float*)d_in[10];
    float* out = (float*)d_out;

    char* ws = (char*)d_ws;
    // Workspace map (peak ~128.3 MB):
    //  phase A (conv): xphi/xplo/cphi/cplo/wchi/wclo @ 0..19.3MB, xe @67.1MB
    //  phase B: h1 @0 (33.5MB) | h2 @67.1MB (33.5MB)
    //  phase C: h3g @0 (67.1MB, over dead h1)
    unsigned short* xphi = (unsigned short*)(ws);
    unsigned short* xplo = (unsigned short*)(ws + 4227072);
    unsigned short* cphi = (unsigned short*)(ws + 8454144);
    unsigned short* cplo = (unsigned short*)(ws + 12681216);
    unsigned short* wchi = (unsigned short*)(ws + 16908288);
    unsigned short* wclo = (unsigned short*)(ws + 18087936);
    unsigned short* h1   = (unsigned short*)(ws);                 // 33.5 MB
    unsigned short* h2   = (unsigned short*)(ws + 67108864);      // 33.5 MB
    float*          h3g  = (float*)(ws);                          // 67.1 MB
    unsigned short* xe   = (unsigned short*)(ws + 67108864);      // 16.8 MB (phase A/B1)
    unsigned short* w1hi = (unsigned short*)(ws + 83886080);
    unsigned short* w1lo = (unsigned short*)(ws + 92274688);
    unsigned short* w2b  = (unsigned short*)(ws + 100663296);
    unsigned short* w3b  = (unsigned short*)(ws + 117440512);
    float* logits  = (float*)(ws + 134217728);
    int*   cnt     = (int*)(ws + 134283264);
    float* gates   = (float*)(ws + 134284288);
    int*   list    = (int*)(ws + 134349824);
    int*   rowidx  = (int*)(ws + 134415360);     // 16 KB

    // prep: padzero + x-split + conv-w split + logits/cnt zero (593 blocks)
    prep_all<<<593, 256, 0, stream>>>(x, conv_w, xphi, xplo, cphi, cplo,
                                      wchi, wclo, logits);

    // Router convs on MFMA (64x64 tiles, 4 blocks/CU). Extra grid rows:
    //   conv1: rows [4,8) = w1 cvt (512); rows [8,40) = downsample (4096)
    //   conv2: rows [4,12) = w2 cvt (1024)
    //   conv3: rows [4,12) = w3 cvt (1024)
    const int WL = 3 * Dd * Dd;
    conv_mfma<0, 1, 4, 1><<<dim3(Bb * Ll / 64, Dd / 64 + 4 + 32), 256, 0, stream>>>(
        xphi, xplo, wchi + 0 * WL, wclo + 0 * WL, conv_b + 0 * Dd, cphi, cplo,
        nullptr, nullptr, w1, w1hi, w1lo, x, xe, 1);
    conv_mfma<0, 2, 8, 0><<<dim3(Bb * Ll / 64, Dd / 64 + 8), 256, 0, stream>>>(
        cphi, cplo, wchi + 1 * WL, wclo + 1 * WL, conv_b + 1 * Dd, xphi, xplo,
        nullptr, nullptr, w2, w2b, nullptr, nullptr, nullptr, 2);
    conv_mfma<1, 2, 8, 0><<<dim3(Bb * Ll / 64, Dd / 64 + 8), 256, 0, stream>>>(
        xphi, xplo, wchi + 2 * WL, wclo + 2 * WL, conv_b + 2 * Dd, nullptr, nullptr,
        fl_w, logits, w3, w3b, nullptr, nullptr, nullptr, 4);

    // grid-parallel router tail (tile table derived inline in gemm_sp)
    gates_topk<<<NTOK / 256, 256, 0, stream>>>(logits, fl_b, gates, cnt, list, rowidx);

    // GEMM1 sparse (gathered A from xe, per-expert K-cap, w1 split 2-pass)
    gemm_sp<0, 1, 1><<<dim3(16, MAXTILES), 256, 0, stream>>>(
        xe, w1hi, w1lo, b1, nullptr, cnt, list, h1, nullptr, NTOK, Hh, LMAXc);

    // GEMM2 sparse (compact->compact, K=1024, plain bf16 B, BK=128)
    gemm_sp<0, 0, 0><<<dim3(16, MAXTILES), 256, 0, stream>>>(
        h1, w2b, nullptr, b2, nullptr, cnt, list, h2, nullptr, NTOK, Hh, Hh);

    // GEMM3 sparse (compact A, plain bf16 B, gated fp32 store — NO atomics)
    gemm_sp<1, 0, 0><<<dim3(16, MAXTILES), 256, 0, stream>>>(
        h2, w3b, nullptr, b3, gates, cnt, list, nullptr, h3g, NTOK, Hh, Hh);

    // gather 2 gated rows per token, sum, write transposed output
    combine_out<<<dim3(Dd / 32, Hh / 32, Bb), 256, 0, stream>>>(h3g, rowidx, out);
}

// Round 21
// 283.373 us; speedup vs baseline: 1.0170x; 1.0107x over previous
//
#include <hip/hip_runtime.h>
#include <math.h>

#define Bb 8
#define Ll 1024
#define Dd 256
#define Ee 8
#define Hh 1024
#define LMAXc 512
#define NTOK (Bb*Dd)   // 2048
#define LPAD 1032      // 4 + 1024 + 4 padded token rows per batch
#define MAXTILES 72    // worst-case sum_e ceil(cnt[e]/64): 4096/64 + 7

typedef short bf16x8 __attribute__((ext_vector_type(8)));
typedef float f32x4 __attribute__((ext_vector_type(4)));
typedef unsigned short u16x8 __attribute__((ext_vector_type(8)));

__device__ __forceinline__ float gelu_f(float x) {
    return 0.5f * x * (1.0f + erff(x * 0.70710678118654752440f));
}
__device__ __forceinline__ unsigned short f2b(float x) {          // RTN fp32->bf16
    unsigned int u = __float_as_uint(x);
    return (unsigned short)((u + 0x7fffu + ((u >> 16) & 1u)) >> 16);
}
__device__ __forceinline__ float b2f(unsigned short h) {
    return __uint_as_float(((unsigned int)h) << 16);
}
__device__ __forceinline__ void gl_lds16(const void* g, void* l) {
    __builtin_amdgcn_global_load_lds((const __attribute__((address_space(1))) unsigned int*)g,
                                     (__attribute__((address_space(3))) unsigned int*)l, 16, 0, 0);
}

// ============================================================================
// prep_all v4: ONLY what conv1 needs + logits zeroing. Downsample rides
// conv1's grid; memset folded in here.
//   [0,32)     : zero pad rows of xphi/xplo/cphi/cplo
//   [32,288)   : pad+split x -> [B][LPAD][D] bf16 hi/lo planes (oct, ILP4)
//   [288,576)  : conv weights [3][D][D][3] -> split planes
//   [576,593)  : zero logits (65536 B) + cnt (64 B)
// ============================================================================
__global__ __launch_bounds__(256) void prep_all(
    const float* __restrict__ x, const float* __restrict__ cw,
    unsigned short* __restrict__ xhi, unsigned short* __restrict__ xlo,
    unsigned short* __restrict__ chi, unsigned short* __restrict__ clo,
    unsigned short* __restrict__ wchi, unsigned short* __restrict__ wclo,
    float* __restrict__ zbase)
{
    int blk = blockIdx.x;
    int t = threadIdx.x;
    if (blk < 32) {
        // zero pad rows: 4 buffers x (8 batches x 8 rows x 256 elems)
        int u = blk * 256 + t;                     // [0, 8192)
        int f = u >> 11;
        int rem = u & 2047;
        int b = rem >> 8;
        int r2 = rem & 255;
        int row = r2 >> 5;
        int col = (r2 & 31) * 8;
        int padrow = (row < 4) ? row : (1024 + row);
        unsigned short* buf = (f == 0) ? xhi : (f == 1) ? xlo : (f == 2) ? chi : clo;
        u16x8 z = {0, 0, 0, 0, 0, 0, 0, 0};
        *(u16x8*)(buf + (size_t)(b * LPAD + padrow) * Dd + col) = z;
    } else if (blk < 288) {
        // x split: 262144 octs (8 floats), ILP4, 16B hi + 16B lo stores
        int cb = blk - 32;
        const float4* s4 = (const float4*)x;
        size_t ob = (size_t)cb * 1024 + t;
        float4 v[8];
        #pragma unroll
        for (int it = 0; it < 4; ++it) {
            v[2 * it]     = s4[(ob + it * 256) * 2];
            v[2 * it + 1] = s4[(ob + it * 256) * 2 + 1];
        }
        #pragma unroll
        for (int it = 0; it < 4; ++it) {
            size_t o = ob + it * 256;
            int d8 = (int)(o & 31), l = (int)((o >> 5) & 1023), b = (int)(o >> 15);
            size_t ooff = (size_t)(b * LPAD + 4 + l) * Dd + d8 * 8;
            float vv[8] = {v[2*it].x, v[2*it].y, v[2*it].z, v[2*it].w,
                           v[2*it+1].x, v[2*it+1].y, v[2*it+1].z, v[2*it+1].w};
            u16x8 hv, lv;
            #pragma unroll
            for (int q = 0; q < 8; ++q) {
                unsigned short h = f2b(vv[q]);
                hv[q] = (short)h;
                lv[q] = (short)f2b(vv[q] - b2f(h));
            }
            *(u16x8*)(xhi + ooff) = hv;
            *(u16x8*)(xlo + ooff) = lv;
        }
    } else if (blk < 576) {
        // conv weights: 589824 outputs; thread = 8 consecutive outputs
        int cb = blk - 288;                        // [0, 288)
        int idx0 = (cb * 256 + t) * 8;
        float vv[8];
        #pragma unroll
        for (int q = 0; q < 8; ++q) {
            int idx = idx0 + q;
            int i = idx & (Dd - 1);
            int o = (idx >> 8) & (Dd - 1);
            int lk = idx >> 16;
            int layer = lk / 3;
            int k = lk % 3;
            vv[q] = cw[(((size_t)layer * Dd + o) * Dd + i) * 3 + k];
        }
        u16x8 hv, lv;
        #pragma unroll
        for (int q = 0; q < 8; ++q) {
            unsigned short h = f2b(vv[q]);
            hv[q] = (short)h;
            lv[q] = (short)f2b(vv[q] - b2f(h));
        }
        *(u16x8*)(wchi + idx0) = hv;
        *(u16x8*)(wclo + idx0) = lv;
    } else {
        // zero logits (65536 B) + cnt (64 B) = 4100 x 16B
        int idx = (blk - 576) * 256 + t;
        if (idx < 4100) {
            u16x8 z = {0, 0, 0, 0, 0, 0, 0, 0};
            *(u16x8*)((char*)zbase + (size_t)idx * 16) = z;
        }
    }
}

// ============================================================================
// conv_mfma (R12 structure, 4 blocks/CU): dilated conv as MFMA NT-GEMM,
// 3-pass split, 64x64 tile, 4 waves (2x2 of 32x32), BK=64.
// MODE 0: split hi/lo output planes.  MODE 1: fused router-logits epilogue.
// CVT rows [4, 4+NCVT): stream fp32 expert weights -> bf16 planes.
// DS=1 (conv1 only): downsample x -> xe rides the CU slack.
// ============================================================================
template<int MODE, int CVT, int NCVT, int DS>
__global__ __launch_bounds__(256, 4) void conv_mfma(
    const unsigned short* __restrict__ inhi, const unsigned short* __restrict__ inlo,
    const unsigned short* __restrict__ whiL, const unsigned short* __restrict__ wloL,
    const float* __restrict__ bias,
    unsigned short* __restrict__ outhi, unsigned short* __restrict__ outlo,
    const float* __restrict__ flw, float* __restrict__ logits,
    const float* __restrict__ cvsrc, unsigned short* __restrict__ cvd1,
    unsigned short* __restrict__ cvd2,
    const float* __restrict__ dsx, unsigned short* __restrict__ dsxe, int dil)
{
    __shared__ char smem[32768];

    if (DS && blockIdx.y >= (Dd / 64) + NCVT) {
        // downsample: u = (e*8 + b)*64 + c;  j0 = c*8; threads = d
        int u = (blockIdx.y - (Dd / 64) - NCVT) * 128 + blockIdx.x;  // [0,4096)
        int e = u >> 9;
        int b = (u >> 6) & 7;
        int c = u & 63;
        int f = e + 2;
        int Li = Ll / f;
        int j0 = c * 8;
        if (j0 >= Li) return;
        int d = threadIdx.x;
        float invf = 1.0f / (float)f;
        int lim = Li - 1;
        float v[8] = {};
        for (int r = 0; r < f; ++r) {
            #pragma unroll
            for (int jj = 0; jj < 8; ++jj) {
                int j = j0 + jj; if (j > lim) j = lim;
                v[jj] += dsx[((size_t)(b * Ll + j * f + r)) * Dd + d];
            }
        }
        size_t obase = ((size_t)(e * NTOK + b * 256 + d)) * LMAXc + j0;
        if (j0 + 8 <= Li) {
            u16x8 hv;
            #pragma unroll
            for (int q = 0; q < 8; ++q) hv[q] = (short)f2b(v[q] * invf);
            *(u16x8*)(dsxe + obase) = hv;
        } else {
            for (int jj = 0; jj < Li - j0; ++jj)
                dsxe[obase + jj] = f2b(v[jj] * invf);
        }
        return;
    }

    if (CVT && blockIdx.y >= (Dd / 64)) {
        int cb = (blockIdx.y - Dd / 64) * 128 + blockIdx.x;
        int t = threadIdx.x;
        const float4* s4 = (const float4*)cvsrc;
        size_t ob = (size_t)cb * 1024 + t;
        float4 v[8];
        #pragma unroll
        for (int it = 0; it < 4; ++it) {
            v[2 * it]     = s4[(ob + it * 256) * 2];
            v[2 * it + 1] = s4[(ob + it * 256) * 2 + 1];
        }
        #pragma unroll
        for (int it = 0; it < 4; ++it) {
            size_t o = ob + it * 256;
            float vv[8] = {v[2*it].x, v[2*it].y, v[2*it].z, v[2*it].w,
                           v[2*it+1].x, v[2*it+1].y, v[2*it+1].z, v[2*it+1].w};
            u16x8 hv, lv;
            #pragma unroll
            for (int q = 0; q < 8; ++q) {
                unsigned short h = f2b(vv[q]);
                hv[q] = (short)h;
                if (CVT == 1) lv[q] = (short)f2b(vv[q] - b2f(h));
            }
            *(u16x8*)(cvd1 + o * 8) = hv;
            if (CVT == 1) *(u16x8*)(cvd2 + o * 8) = lv;
        }
        return;
    }

    char* sAhi = smem;
    char* sAlo = smem + 8192;
    char* sBhi = smem + 16384;
    char* sBlo = smem + 24576;

    const int t = threadIdx.x;
    const int lane = t & 63, w = t >> 6;
    const int r16 = lane & 15, quad = lane >> 4;
    const int wr = w >> 1, wc = w & 1;
    const int row0 = blockIdx.x * 64;
    const int col0 = blockIdx.y * 64;
    const int b = row0 >> 10, l0 = row0 & 1023;

    int aoff[2], boff[2];
    #pragma unroll
    for (int i = 0; i < 2; ++i) {
        int ra = wr * 32 + i * 16 + r16;
        aoff[i] = ra * 64 + ((quad ^ ((ra >> 1) & 3)) << 4);
        int rb = wc * 32 + i * 16 + r16;
        boff[i] = rb * 64 + ((quad ^ ((rb >> 1) & 3)) << 4);
    }
    const int rs = t >> 2, ce = ((t & 3) ^ ((rs >> 1) & 3)) << 3;
    const unsigned short* gAhi = inhi + (size_t)(b * LPAD + 4 + l0 + rs) * Dd + ce;
    const unsigned short* gAlo = inlo + (size_t)(b * LPAD + 4 + l0 + rs) * Dd + ce;

    f32x4 acc[2][2];
    const f32x4 zero4 = {0.f, 0.f, 0.f, 0.f};
    #pragma unroll
    for (int i = 0; i < 2; ++i)
        #pragma unroll
        for (int j = 0; j < 2; ++j) acc[i][j] = zero4;

    for (int tap = 0; tap < 3; ++tap) {
        const int sh = (tap - 1) * dil;
        const unsigned short* pAhi = gAhi + sh * Dd;
        const unsigned short* pAlo = gAlo + sh * Dd;
        const unsigned short* gBhi = whiL + ((size_t)tap * Dd + col0 + rs) * Dd + ce;
        const unsigned short* gBlo = wloL + ((size_t)tap * Dd + col0 + rs) * Dd + ce;
        for (int kb = 0; kb < Dd; kb += 64) {
            gl_lds16(pAhi + kb,      sAhi + (w << 10));
            gl_lds16(pAhi + kb + 32, sAhi + 4096 + (w << 10));
            gl_lds16(pAlo + kb,      sAlo + (w << 10));
            gl_lds16(pAlo + kb + 32, sAlo + 4096 + (w << 10));
            gl_lds16(gBhi + kb,      sBhi + (w << 10));
            gl_lds16(gBhi + kb + 32, sBhi + 4096 + (w << 10));
            gl_lds16(gBlo + kb,      sBlo + (w << 10));
            gl_lds16(gBlo + kb + 32, sBlo + 4096 + (w << 10));
            __syncthreads();
            #pragma unroll
            for (int h = 0; h < 2; ++h) {
                const int ho = h * 4096;
                bf16x8 ah[2], al[2], bh[2], bl[2];
                #pragma unroll
                for (int i = 0; i < 2; ++i) {
                    ah[i] = *(const bf16x8*)(sAhi + ho + aoff[i]);
                    al[i] = *(const bf16x8*)(sAlo + ho + aoff[i]);
                    bh[i] = *(const bf16x8*)(sBhi + ho + boff[i]);
                    bl[i] = *(const bf16x8*)(sBlo + ho + boff[i]);
                }
                #pragma unroll
                for (int mi = 0; mi < 2; ++mi)
                    #pragma unroll
                    for (int ni = 0; ni < 2; ++ni) {
                        acc[mi][ni] = __builtin_amdgcn_mfma_f32_16x16x32_bf16(ah[mi], bh[ni], acc[mi][ni], 0, 0, 0);
                        acc[mi][ni] = __builtin_amdgcn_mfma_f32_16x16x32_bf16(ah[mi], bl[ni], acc[mi][ni], 0, 0, 0);
                        acc[mi][ni] = __builtin_amdgcn_mfma_f32_16x16x32_bf16(al[mi], bh[ni], acc[mi][ni], 0, 0, 0);
                    }
            }
            __syncthreads();
        }
    }

    int cc[2]; float bv[2];
    #pragma unroll
    for (int ni = 0; ni < 2; ++ni) {
        cc[ni] = col0 + wc * 32 + ni * 16 + r16;
        bv[ni] = bias[cc[ni]];
    }
    if (MODE == 0) {
        #pragma unroll
        for (int mi = 0; mi < 2; ++mi) {
            int lb = l0 + wr * 32 + mi * 16 + quad * 4;
            #pragma unroll
            for (int reg = 0; reg < 4; ++reg) {
                int l = lb + reg;
                #pragma unroll
                for (int ni = 0; ni < 2; ++ni) {
                    float v = gelu_f(acc[mi][ni][reg] + bv[ni]);
                    size_t o = (size_t)(b * LPAD + 4 + l) * Dd + cc[ni];
                    unsigned short h = f2b(v);
                    outhi[o] = h;
                    outlo[o] = f2b(v - b2f(h));
                }
            }
        }
    } else {
        // fused logits: LDS partials over the 64x64 tile, then 512 atomics.
        float* wl   = (float*)smem;            // [64 l_local][8 e]
        float* slog = (float*)(smem + 2048);   // [64 d_local][8 e]
        for (int i = t; i < 512; i += 256) {
            int ll = i >> 3, e = i & 7;
            wl[i] = flw[e * Ll + l0 + ll];
            slog[i] = 0.0f;
        }
        __syncthreads();
        float part[2][8];
        #pragma unroll
        for (int ni = 0; ni < 2; ++ni)
            #pragma unroll
            for (int e = 0; e < 8; ++e) part[ni][e] = 0.0f;
        #pragma unroll
        for (int mi = 0; mi < 2; ++mi) {
            #pragma unroll
            for (int reg = 0; reg < 4; ++reg) {
                int ll = wr * 32 + mi * 16 + quad * 4 + reg;
                #pragma unroll
                for (int ni = 0; ni < 2; ++ni) {
                    float v = gelu_f(acc[mi][ni][reg] + bv[ni]);
                    #pragma unroll
                    for (int e = 0; e < 8; ++e) part[ni][e] += v * wl[ll * 8 + e];
                }
            }
        }
        #pragma unroll
        for (int ni = 0; ni < 2; ++ni) {
            int dl = wc * 32 + ni * 16 + r16;
            #pragma unroll
            for (int e = 0; e < 8; ++e) atomicAdd(&slog[dl * 8 + e], part[ni][e]);
        }
        __syncthreads();
        for (int i = t; i < 512; i += 256) {
            int dl = i >> 3, e = i & 7;
            atomicAdd(&logits[(size_t)(b * Dd + col0 + dl) * Ee + e], slog[i]);
        }
    }
}

// ============================================================================
// Sparse expert GEMM (64x64 tiles). Expert/tile derived inline from cnt[]
// prefix. MODE 0: gelu -> bf16 compact. MODE 1: gated fp32 store, no atomics.
// ============================================================================
template<int MODE, int GATHER, int TWOPASS>
__global__ __launch_bounds__(256, 4) void gemm_sp(
    const unsigned short* __restrict__ AG,
    const unsigned short* __restrict__ BhiG, const unsigned short* __restrict__ BloG,
    const float* __restrict__ biasG, const float* __restrict__ gates,
    const int* __restrict__ cntG, const int* __restrict__ listG,
    unsigned short* __restrict__ Cout, float* __restrict__ outf,
    int M, int N, int K)
{
    // derive (expert, row-tile) from cnt prefix — uniform across the block
    int m = blockIdx.y, e;
    #pragma unroll
    for (e = 0; e < Ee; ++e) {
        int te = (cntG[e] + 63) >> 6;
        if (m < te) break;
        m -= te;
    }
    if (e == Ee) return;
    const int row0 = m * 64;
    const int cn = cntG[e];

    constexpr int NCH = TWOPASS ? 2 : 4;          // 32-col chunks per K-iter
    __shared__ char smem[TWOPASS ? 24576 : 32768];
    char* sA   = smem;
    char* sBhi = smem + NCH * 4096;
    char* sBlo = smem + 2 * NCH * 4096;           // TWOPASS only

    const unsigned short* Bhi = BhiG + (size_t)e * N * K;
    const unsigned short* Blo = TWOPASS ? (BloG + (size_t)e * N * K) : nullptr;
    const float* bias = biasG + (size_t)e * N;

    int Keff = K;
    if (GATHER) {
        int Li = Ll / (e + 2);
        Keff = ((Li + 63) >> 6) << 6;
    }

    const int t = threadIdx.x;
    const int lane = t & 63, w = t >> 6;
    const int r16 = lane & 15, quad = lane >> 4;
    const int wr = w >> 1, wc = w & 1;
    const int col0 = blockIdx.x * 64;

    int aoff[2], boff[2];
    #pragma unroll
    for (int i = 0; i < 2; ++i) {
        int ra = wr * 32 + i * 16 + r16;
        aoff[i] = ra * 64 + ((quad ^ ((ra >> 1) & 3)) << 4);
        int rb = wc * 32 + i * 16 + r16;
        boff[i] = rb * 64 + ((quad ^ ((rb >> 1) & 3)) << 4);
    }
    const int r0s = t >> 2, c0s = ((t & 3) ^ ((r0s >> 1) & 3)) << 3;
    int ri = row0 + r0s; if (ri > cn - 1) ri = cn - 1;
    const int ar = GATHER ? listG[e * NTOK + ri] : ri;
    const unsigned short* gA  = AG + ((size_t)e * M + ar) * K + c0s;
    const unsigned short* gB  = Bhi + (size_t)(col0 + r0s) * K + c0s;
    const unsigned short* gBl = TWOPASS ? (Blo + (size_t)(col0 + r0s) * K + c0s) : nullptr;
    const int wofs = w << 10;

    f32x4 acc[2][2];
    const f32x4 zero4 = {0.f, 0.f, 0.f, 0.f};
    #pragma unroll
    for (int i = 0; i < 2; ++i)
        #pragma unroll
        for (int j = 0; j < 2; ++j) acc[i][j] = zero4;

    for (int k0 = 0; k0 < Keff; k0 += NCH * 32) {
        #pragma unroll
        for (int c = 0; c < NCH; ++c) {
            gl_lds16(gA + k0 + c * 32, sA + c * 4096 + wofs);
            gl_lds16(gB + k0 + c * 32, sBhi + c * 4096 + wofs);
        }
        if (TWOPASS) {
            #pragma unroll
            for (int c = 0; c < NCH; ++c)
                gl_lds16(gBl + k0 + c * 32, sBlo + c * 4096 + wofs);
        }
        __syncthreads();
        #pragma unroll
        for (int h = 0; h < NCH; ++h) {
            const int ho = h * 4096;
            bf16x8 ah[2], bh[2];
            #pragma unroll
            for (int i = 0; i < 2; ++i) {
                ah[i] = *(const bf16x8*)(sA + ho + aoff[i]);
                bh[i] = *(const bf16x8*)(sBhi + ho + boff[i]);
            }
            #pragma unroll
            for (int mi = 0; mi < 2; ++mi)
                #pragma unroll
                for (int ni = 0; ni < 2; ++ni)
                    acc[mi][ni] = __builtin_amdgcn_mfma_f32_16x16x32_bf16(ah[mi], bh[ni], acc[mi][ni], 0, 0, 0);
            if (TWOPASS) {
                bf16x8 bl[2];
                #pragma unroll
                for (int i = 0; i < 2; ++i) bl[i] = *(const bf16x8*)(sBlo + ho + boff[i]);
                #pragma unroll
                for (int mi = 0; mi < 2; ++mi)
                    #pragma unroll
                    for (int ni = 0; ni < 2; ++ni)
                        acc[mi][ni] = __builtin_amdgcn_mfma_f32_16x16x32_bf16(ah[mi], bl[ni], acc[mi][ni], 0, 0, 0);
            }
        }
        __syncthreads();
    }

    int cc[2]; float bv[2];
    #pragma unroll
    for (int ni = 0; ni < 2; ++ni) {
        cc[ni] = col0 + wc * 32 + ni * 16 + r16;
        bv[ni] = bias[cc[ni]];
    }
    if (MODE == 0) {
        unsigned short* CE = Cout + (size_t)e * M * N;
        #pragma unroll
        for (int mi = 0; mi < 2; ++mi) {
            int rb = row0 + wr * 32 + mi * 16 + quad * 4;
            #pragma unroll
            for (int reg = 0; reg < 4; ++reg) {
                size_t roff = (size_t)(rb + reg) * N;
                #pragma unroll
                for (int ni = 0; ni < 2; ++ni)
                    CE[roff + cc[ni]] = f2b(gelu_f(acc[mi][ni][reg] + bv[ni]));
            }
        }
    } else {
        // gated plain-store epilogue: h3g row = e*NTOK + compact index
        #pragma unroll
        for (int mi = 0; mi < 2; ++mi) {
            int rb = row0 + wr * 32 + mi * 16 + quad * 4;
            #pragma unroll
            for (int reg = 0; reg < 4; ++reg) {
                int i = rb + reg;
                if (i < cn) {
                    int tok = listG[e * NTOK + i];
                    float g = gates[(size_t)tok * Ee + e];
                    size_t roff = ((size_t)e * NTOK + i) * N;
                    #pragma unroll
                    for (int ni = 0; ni < 2; ++ni)
                        outf[roff + cc[ni]] = g * (acc[mi][ni][reg] + bv[ni]);
                }
            }
        }
    }
}

// ============================ router tail ==============================

// gates_topk: grid-parallel (8 blocks x 256 thr = 1 thr/token).
__global__ __launch_bounds__(256) void gates_topk(const float* __restrict__ logits,
                                                  const float* __restrict__ fl_b,
                                                  float* __restrict__ gates,
                                                  int* __restrict__ cnt,
                                                  int* __restrict__ list,
                                                  int* __restrict__ rowidx) {
    const int tok = blockIdx.x * 256 + threadIdx.x;
    const int lane = threadIdx.x & 63;
    const unsigned long long ltmask = (1ull << lane) - 1ull;

    float s[Ee];
    #pragma unroll
    for (int e = 0; e < Ee; ++e) {
        float z = logits[tok * Ee + e] + fl_b[e];
        s[e] = 1.0f / (1.0f + expf(-z));
    }
    float mx = s[0];
    #pragma unroll
    for (int e = 1; e < Ee; ++e) mx = fmaxf(mx, s[e]);
    float p[Ee];
    #pragma unroll
    for (int e = 0; e < Ee; ++e) p[e] = expf(s[e] - mx);
    int i1 = 0;
    #pragma unroll
    for (int e = 1; e < Ee; ++e) if (p[e] > p[i1]) i1 = e;
    int i2 = (i1 == 0) ? 1 : 0;
    #pragma unroll
    for (int e = 0; e < Ee; ++e) {
        if (e == i1 || e == i2) continue;
        if (p[e] > p[i2]) i2 = e;
    }
    float inv = 1.0f / (p[i1] + p[i2]);
    #pragma unroll
    for (int e = 0; e < Ee; ++e) gates[tok * Ee + e] = 0.0f;
    gates[tok * Ee + i1] = p[i1] * inv;
    gates[tok * Ee + i2] = p[i2] * inv;

    #pragma unroll
    for (int slot = 0; slot < 2; ++slot) {
        int ie = slot ? i2 : i1;
        for (int e = 0; e < Ee; ++e) {
            unsigned long long m = __ballot(ie == e);
            if (m) {
                int leader = __ffsll((long long)m) - 1;
                int base = 0;
                if (lane == leader) base = atomicAdd(&cnt[e], (int)__popcll(m));
                base = __shfl(base, leader);
                if (ie == e) {
                    int pos = base + (int)__popcll(m & ltmask);
                    list[e * NTOK + pos] = tok;
                    rowidx[tok * 2 + slot] = e * NTOK + pos;
                }
            }
        }
    }
}

// combine_out: out[b][o][d] = h3g[r0][o] + h3g[r1][o]  (rows pre-gated)
__global__ __launch_bounds__(256) void combine_out(const float* __restrict__ h3g,
                                                   const int* __restrict__ rowidx,
                                                   float* __restrict__ out) {
    __shared__ float tile[32][33];
    int b = blockIdx.z;
    int d0 = blockIdx.x * 32;
    int o0 = blockIdx.y * 32;
    int tx = threadIdx.x & 31, ty = threadIdx.x >> 5;
    for (int i = 0; i < 32; i += 8) {
        int tok = b * Dd + d0 + ty + i;
        int r0 = rowidx[tok * 2];
        int r1 = rowidx[tok * 2 + 1];
        tile[ty + i][tx] = h3g[(size_t)r0 * Hh + o0 + tx] + h3g[(size_t)r1 * Hh + o0 + tx];
    }
    __syncthreads();
    for (int i = 0; i < 32; i += 8)
        out[((size_t)b * Hh + o0 + ty + i) * Dd + d0 + tx] = tile[tx][ty + i];
}

extern "C" void kernel_launch(void* const* d_in, const int* in_sizes, int n_in,
                              void* d_out, int out_size, void* d_ws, size_t ws_size,
                              hipStream_t stream) {
    const float* x       = (const float*)d_in[0];
    const float* conv_w  = (const float*)d_in[1];
    const float* conv_b  = (const float*)d_in[2];
    const float* fl_w    = (const float*)d_in[3];
    const float* fl_b    = (const float*)d_in[4];
    const float* w1      = (const float*)d_in[5];
    const float* b1      = (const float*)d_in[6];
    const float* w2      = (const float*)d_in[7];
    const float* b2      = (const float*)d_in[8];
    const float* w3      = (const float*)d_in[9];
    const float* b3      = (const float*)d_in[10];
    float* out = (float*)d_out;

    char* ws = (char*)d_ws;
    // Workspace map (peak ~128.3 MB):
    //  phase A (conv): xphi/xplo/cphi/cplo/wchi/wclo @ 0..19.3MB, xe @67.1MB
    //  phase B: h1 @0 (33.5MB) | h2 @67.1MB (33.5MB)
    //  phase C: h3g @0 (67.1MB, over dead h1)
    unsigned short* xphi = (unsigned short*)(ws);
    unsigned short* xplo = (unsigned short*)(ws + 4227072);
    unsigned short* cphi = (unsigned short*)(ws + 8454144);
    unsigned short* cplo = (unsigned short*)(ws + 12681216);
    unsigned short* wchi = (unsigned short*)(ws + 16908288);
    unsigned short* wclo = (unsigned short*)(ws + 18087936);
    unsigned short* h1   = (unsigned short*)(ws);                 // 33.5 MB
    unsigned short* h2   = (unsigned short*)(ws + 67108864);      // 33.5 MB
    float*          h3g  = (float*)(ws);                          // 67.1 MB
    unsigned short* xe   = (unsigned short*)(ws + 67108864);      // 16.8 MB (phase A/B1)
    unsigned short* w1hi = (unsigned short*)(ws + 83886080);
    unsigned short* w1lo = (unsigned short*)(ws + 92274688);
    unsigned short* w2b  = (unsigned short*)(ws + 100663296);
    unsigned short* w3b  = (unsigned short*)(ws + 117440512);
    float* logits  = (float*)(ws + 134217728);
    int*   cnt     = (int*)(ws + 134283264);
    float* gates   = (float*)(ws + 134284288);
    int*   list    = (int*)(ws + 134349824);
    int*   rowidx  = (int*)(ws + 134415360);     // 16 KB

    // prep: padzero + x-split + conv-w split + logits/cnt zero (593 blocks)
    prep_all<<<593, 256, 0, stream>>>(x, conv_w, xphi, xplo, cphi, cplo,
                                      wchi, wclo, logits);

    // Router convs on MFMA (64x64 tiles, 4 blocks/CU). Extra grid rows:
    //   conv1: rows [4,8) = w1 cvt (512); rows [8,40) = downsample (4096)
    //   conv2: rows [4,12) = w2 cvt (1024)
    //   conv3: rows [4,12) = w3 cvt (1024)
    const int WL = 3 * Dd * Dd;
    conv_mfma<0, 1, 4, 1><<<dim3(Bb * Ll / 64, Dd / 64 + 4 + 32), 256, 0, stream>>>(
        xphi, xplo, wchi + 0 * WL, wclo + 0 * WL, conv_b + 0 * Dd, cphi, cplo,
        nullptr, nullptr, w1, w1hi, w1lo, x, xe, 1);
    conv_mfma<0, 2, 8, 0><<<dim3(Bb * Ll / 64, Dd / 64 + 8), 256, 0, stream>>>(
        cphi, cplo, wchi + 1 * WL, wclo + 1 * WL, conv_b + 1 * Dd, xphi, xplo,
        nullptr, nullptr, w2, w2b, nullptr, nullptr, nullptr, 2);
    conv_mfma<1, 2, 8, 0><<<dim3(Bb * Ll / 64, Dd / 64 + 8), 256, 0, stream>>>(
        xphi, xplo, wchi + 2 * WL, wclo + 2 * WL, conv_b + 2 * Dd, nullptr, nullptr,
        fl_w, logits, w3, w3b, nullptr, nullptr, nullptr, 4);

    // grid-parallel router tail (tile table derived inline in gemm_sp)
    gates_topk<<<NTOK / 256, 256, 0, stream>>>(logits, fl_b, gates, cnt, list, rowidx);

    // GEMM1 sparse (gathered A from xe, per-expert K-cap, w1 split 2-pass)
    gemm_sp<0, 1, 1><<<dim3(16, MAXTILES), 256, 0, stream>>>(
        xe, w1hi, w1lo, b1, nullptr, cnt, list, h1, nullptr, NTOK, Hh, LMAXc);

    // GEMM2 sparse (compact->compact, K=1024, plain bf16 B, BK=128)
    gemm_sp<0, 0, 0><<<dim3(16, MAXTILES), 256, 0, stream>>>(
        h1, w2b, nullptr, b2, nullptr, cnt, list, h2, nullptr, NTOK, Hh, Hh);

    // GEMM3 sparse (compact A, plain bf16 B, gated fp32 store — NO atomics)
    gemm_sp<1, 0, 0><<<dim3(16, MAXTILES), 256, 0, stream>>>(
        h2, w3b, nullptr, b3, gates, cnt, list, nullptr, h3g, NTOK, Hh, Hh);

    // gather 2 gated rows per token, sum, write transposed output
    combine_out<<<dim3(Dd / 32, Hh / 32, Bb), 256, 0, stream>>>(h3g, rowidx, out);
}